// Round 3
// baseline (1410.804 us; speedup 1.0000x reference)
//
#include <hip/hip_runtime.h>
#include <math.h>

// ---- problem constants ----
#define K_NB 20
#define DIM  128     // D
#define TDIM 128     // TD
#define IMP  100
#define DKQ  256     // DK
#define HID  1024    // H
#define FEAT 484
#define FB   384     // base feature cols (nx|ex|etx); imp handled via h
#define NB1  5120    // B*K rows at depth 1
#define NB2  256     // B rows at depth 2

__device__ __forceinline__ float sigmoidf_(float x) { return 1.f / (1.f + expf(-x)); }

// ---------------------------------------------------------------------------
// P0: precompute VW = [Wv[0:384] ; W2@Wv[384:484]]  (484x256),
//     qc0 = cos(time_b)@Wq[128:256]  (256),  cv0 = b2@Wv[384:484]  (256)
// ---------------------------------------------------------------------------
__global__ __launch_bounds__(256) void precompute_k(
    const float* __restrict__ time_b, const float* __restrict__ imp_b2,
    const float* __restrict__ Wq, const float* __restrict__ Wv,
    const float* __restrict__ W2,
    float* __restrict__ VW, float* __restrict__ qc0, float* __restrict__ cv0)
{
    int b = blockIdx.x, t = threadIdx.x;
    if (b < FB) {
        VW[b * DKQ + t] = Wv[b * DKQ + t];
    } else if (b < FB + IMP) {
        int j = b - FB; float acc = 0.f;
        for (int m = 0; m < IMP; m++) acc += W2[j * IMP + m] * Wv[(FB + m) * DKQ + t];
        VW[b * DKQ + t] = acc;
    } else if (b == FB + IMP) {
        float acc = 0.f;
        for (int j = 0; j < TDIM; j++) acc += cosf(time_b[j]) * Wq[(DIM + j) * DKQ + t];
        qc0[t] = acc;
    } else {
        float acc = 0.f;
        for (int m = 0; m < IMP; m++) acc += imp_b2[m] * Wv[(FB + m) * DKQ + t];
        cv0[t] = acc;
    }
}

// ---------------------------------------------------------------------------
// CX[i][c] = node_reprs[cid][c] + node_embed[cid][c]
// 4 rows/block, 32 lanes x float4 per row (16 B/lane coalescing sweet spot)
// ---------------------------------------------------------------------------
__global__ __launch_bounds__(128) void cx_gather_k(
    const float* __restrict__ nr, const float* __restrict__ ne,
    const int* __restrict__ cids, float* __restrict__ CX, int nrows)
{
    int r = blockIdx.x * 4 + (threadIdx.x >> 5);
    if (r >= nrows) return;
    int c4 = (threadIdx.x & 31);               // float4 index within the 128-col row
    int nid = cids[r];
    const float4 a = ((const float4*)(nr + (size_t)nid * DIM))[c4];
    const float4 b = ((const float4*)(ne + (size_t)nid * DIM))[c4];
    float4 o; o.x = a.x + b.x; o.y = a.y + b.y; o.z = a.z + b.z; o.w = a.w + b.w;
    ((float4*)(CX + (size_t)r * DIM))[c4] = o;
}

// ---------------------------------------------------------------------------
// Generic f32 GEMM: C[M,N] = (A|A2 concat at asplit)[M,K] @ B  (+bias)*scale
// BT=false: B is [K,N] row-major.  BT=true: B is [N,K] row-major (C=A@B^T).
// BM=128, BN=64, BK=16, 256 threads, 8x4 micro-tile.
// ---------------------------------------------------------------------------
template <bool BT>
__global__ __launch_bounds__(256) void gemm_f32(
    const float* __restrict__ A, const float* __restrict__ A2, int asplit, int lda2,
    const float* __restrict__ B, const float* __restrict__ bias,
    float* __restrict__ C, int M, int N, int K, int lda, int ldb, int ldc, float scale)
{
    __shared__ float As[16][132];
    __shared__ float Bs[16][68];
    const int tid = threadIdx.x;
    const int bm = blockIdx.y * 128, bn = blockIdx.x * 64;
    const int tm = (tid >> 4) * 8, tn = (tid & 15) * 4;
    float acc[8][4] = {};

    for (int k0 = 0; k0 < K; k0 += 16) {
        { // A tile: 128 rows x 16 k, 8 per thread
            int r = tid >> 1, kc = (tid & 1) * 8;
            int gr = bm + r;
#pragma unroll
            for (int i = 0; i < 8; i++) {
                int gk = k0 + kc + i;
                float v = 0.f;
                if (gr < M && gk < K)
                    v = (A2 && gk >= asplit) ? A2[gr * lda2 + (gk - asplit)] : A[gr * lda + gk];
                As[kc + i][r] = v;
            }
        }
        if (!BT) { // B[k][n]
            int kb = tid >> 4, nb = (tid & 15) * 4;
            int gk = k0 + kb;
#pragma unroll
            for (int i = 0; i < 4; i++) {
                int gn = bn + nb + i;
                Bs[kb][nb + i] = (gk < K && gn < N) ? B[gk * ldb + gn] : 0.f;
            }
        } else { // B[n][k] -> Bs[k][n]
            int n = tid >> 2, kc = (tid & 3) * 4;
            int gn = bn + n;
#pragma unroll
            for (int i = 0; i < 4; i++) {
                int gk = k0 + kc + i;
                Bs[kc + i][n] = (gn < N && gk < K) ? B[gn * ldb + gk] : 0.f;
            }
        }
        __syncthreads();
#pragma unroll
        for (int kk = 0; kk < 16; kk++) {
            float a[8], b[4];
#pragma unroll
            for (int i = 0; i < 8; i++) a[i] = As[kk][tm + i];
#pragma unroll
            for (int j = 0; j < 4; j++) b[j] = Bs[kk][tn + j];
#pragma unroll
            for (int i = 0; i < 8; i++)
#pragma unroll
                for (int j = 0; j < 4; j++) acc[i][j] += a[i] * b[j];
        }
        __syncthreads();
    }
#pragma unroll
    for (int i = 0; i < 8; i++) {
        int gm = bm + tm + i;
        if (gm >= M) continue;
#pragma unroll
        for (int j = 0; j < 4; j++) {
            int gn = bn + tn + j;
            if (gn >= N) continue;
            float v = acc[i][j];
            if (bias) v += bias[gn];
            C[gm * ldc + gn] = v * scale;
        }
    }
}

// ---------------------------------------------------------------------------
// Per-center-row attention: build featbase in LDS, scores = feat.kq,
// softmax, write WFB = [sum attn*featbase (384) | sum attn*h (100)].
// One block (256 thr) per row. KQ row: cols [0:384)=base, [384:484)=imp.
// ---------------------------------------------------------------------------
template <int DEPTH>
__global__ __launch_bounds__(256) void attn_rows_k(
    const float* __restrict__ nr, const float* __restrict__ ne,
    const float* __restrict__ ee, const float* __restrict__ h1,
    const int* __restrict__ nids, const int* __restrict__ eids,
    const float* __restrict__ nts, const float* __restrict__ deg,
    const float* __restrict__ re, const float* __restrict__ ts,
    const float* __restrict__ tw, const float* __restrict__ tb,
    const float* __restrict__ iw1, const float* __restrict__ ib1,
    const float* __restrict__ W2,
    const float* __restrict__ KQ, float* __restrict__ WFB)
{
    __shared__ float featb[K_NB][FB + 1];   // pad: column reads hit distinct banks
    __shared__ float h_lds[K_NB][IMP + 4];
    __shared__ float kq_imp[IMP];
    __shared__ float s_lds[K_NB], dt_lds[K_NB], attn_l[K_NB], score[K_NB];
    __shared__ int nid_l[K_NB], eid_l[K_NB];

    const int row = blockIdx.x, tid = threadIdx.x;

    if (tid < K_NB) {
        int nid = nids[row * K_NB + tid];
        nid_l[tid] = nid; eid_l[tid] = eids[row * K_NB + tid];
        float tc = (DEPTH == 1) ? ts[row / K_NB] : ts[row];
        dt_lds[tid] = tc - nts[row * K_NB + tid];
        float rv = re[row * K_NB + tid];
        s_lds[tid] = (rv == 0.f) ? 0.f : deg[row * K_NB + tid] / rv;
    } else if (tid >= 100 && tid < 200) {
        kq_imp[tid - 100] = KQ[row * FEAT + FB + (tid - 100)];
    } else if (tid >= 200 && tid < 200 + K_NB) {
        score[tid - 200] = 0.f;
    }
    // thread-owned kq_base entries (cols tid and 256+tid)
    float kqr1 = KQ[row * FEAT + tid];
    float kqr2 = (tid < FB - 256) ? KQ[row * FEAT + 256 + tid] : 0.f;
    __syncthreads();

    float m2kq_own = 0.f;          // (W2 @ kq_imp)[tid] for tid<100
    if (tid < IMP) {
#pragma unroll 4
        for (int m = 0; m < IMP; m++) m2kq_own += W2[tid * IMP + m] * kq_imp[m];
    }
    // build featbase + h
    for (int r = 0; r < K_NB; r++) {
        int nid = nid_l[r];
        float v;
        if (tid < DIM)
            v = (DEPTH == 1) ? (nr[nid * DIM + tid] + ne[nid * DIM + tid])
                             : h1[(row * K_NB + r) * DIM + tid];
        else
            v = ee[eid_l[r] * DIM + (tid - DIM)];
        featb[r][tid] = v;
        if (tid < TDIM) featb[r][256 + tid] = cosf(dt_lds[r] * tw[tid] + tb[tid]);
        if (tid < IMP)  h_lds[r][tid] = fmaxf(s_lds[r] * iw1[tid] + ib1[tid], 0.f);
    }
    __syncthreads();

    // scores (b2-const term dropped: softmax shift-invariant)
    const int lane = tid & 63;
    for (int r = 0; r < K_NB; r++) {
        float val = featb[r][tid] * kqr1;
        if (tid < 128) val += featb[r][256 + tid] * kqr2;
        if (tid < IMP) val += h_lds[r][tid] * m2kq_own;
#pragma unroll
        for (int off = 32; off >= 1; off >>= 1) val += __shfl_down(val, off);
        if (lane == 0) atomicAdd(&score[r], val);
    }
    __syncthreads();

    if (tid == 0) {
        float mx = -1e30f;
        for (int r = 0; r < K_NB; r++) {
            float sc = (nid_l[r] == 0) ? -1e9f : score[r];
            score[r] = sc; if (sc > mx) mx = sc;
        }
        float sum = 0.f;
        for (int r = 0; r < K_NB; r++) { float e = expf(score[r] - mx); attn_l[r] = e; sum += e; }
        float inv = 1.f / sum;
        for (int r = 0; r < K_NB; r++) attn_l[r] *= inv;
    }
    __syncthreads();

    { // weighted featbase, col = tid
        float a = 0.f;
#pragma unroll 4
        for (int r = 0; r < K_NB; r++) a += attn_l[r] * featb[r][tid];
        WFB[row * FEAT + tid] = a;
    }
    if (tid < 128) { // col = 256+tid
        float a = 0.f;
#pragma unroll 4
        for (int r = 0; r < K_NB; r++) a += attn_l[r] * featb[r][256 + tid];
        WFB[row * FEAT + 256 + tid] = a;
    }
    if (tid >= 128 && tid < 128 + IMP) { // w_h cols
        int j = tid - 128; float a = 0.f;
#pragma unroll 4
        for (int r = 0; r < K_NB; r++) a += attn_l[r] * h_lds[r][j];
        WFB[row * FEAT + FB + j] = a;
    }
}

// ---------------------------------------------------------------------------
// HN = lstm(CTX @ wih[:, {i,g,o}] + b):  h = sig(o)*tanh(sig(i)*tanh(g))
// BM=64, BN=64 (of 1024), K=256. f-gate skipped (c_old = 0).
// ---------------------------------------------------------------------------
__global__ __launch_bounds__(256) void gates_hn_k(
    const float* __restrict__ CTX, const float* __restrict__ wih,
    const float* __restrict__ bias, float* __restrict__ HN, int M)
{
    __shared__ float As[16][68];
    __shared__ float Bs[3][16][68];
    const int tid = threadIdx.x;
    const int bm = blockIdx.y * 64, bn = blockIdx.x * 64;
    const int tm = (tid >> 4) * 4, tn = (tid & 15) * 4;
    float acc[3][4][4] = {};
    const int goff0 = 0, goff1 = 2048, goff2 = 3072;

    for (int k0 = 0; k0 < DKQ; k0 += 16) {
        int r = tid >> 2, kc = (tid & 3) * 4;
#pragma unroll
        for (int i = 0; i < 4; i++) As[kc + i][r] = CTX[(bm + r) * DKQ + k0 + kc + i];
        int kb = tid >> 4, nb = (tid & 15) * 4;
#pragma unroll
        for (int i = 0; i < 4; i++) {
            Bs[0][kb][nb + i] = wih[(k0 + kb) * 4096 + goff0 + bn + nb + i];
            Bs[1][kb][nb + i] = wih[(k0 + kb) * 4096 + goff1 + bn + nb + i];
            Bs[2][kb][nb + i] = wih[(k0 + kb) * 4096 + goff2 + bn + nb + i];
        }
        __syncthreads();
#pragma unroll
        for (int kk = 0; kk < 16; kk++) {
            float a[4], b0[4], b1[4], b2v[4];
#pragma unroll
            for (int i = 0; i < 4; i++) a[i] = As[kk][tm + i];
#pragma unroll
            for (int j = 0; j < 4; j++) {
                b0[j] = Bs[0][kk][tn + j]; b1[j] = Bs[1][kk][tn + j]; b2v[j] = Bs[2][kk][tn + j];
            }
#pragma unroll
            for (int i = 0; i < 4; i++)
#pragma unroll
                for (int j = 0; j < 4; j++) {
                    acc[0][i][j] += a[i] * b0[j];
                    acc[1][i][j] += a[i] * b1[j];
                    acc[2][i][j] += a[i] * b2v[j];
                }
        }
        __syncthreads();
    }
#pragma unroll
    for (int i = 0; i < 4; i++)
#pragma unroll
        for (int j = 0; j < 4; j++) {
            int n = bn + tn + j;
            float iv = acc[0][i][j] + bias[n];
            float gv = acc[1][i][j] + bias[2048 + n];
            float ov = acc[2][i][j] + bias[3072 + n];
            float c = sigmoidf_(iv) * tanhf(gv);
            HN[(bm + tm + i) * HID + n] = sigmoidf_(ov) * tanhf(c);
        }
}

// ---------------------------------------------------------------------------
extern "C" void kernel_launch(void* const* d_in, const int* in_sizes, int n_in,
                              void* d_out, int out_size, void* d_ws, size_t ws_size,
                              hipStream_t stream)
{
    const float* nr   = (const float*)d_in[0];
    const float* ne   = (const float*)d_in[1];
    const float* ee   = (const float*)d_in[2];
    const float* tw   = (const float*)d_in[3];
    const float* tb   = (const float*)d_in[4];
    const float* iw1  = (const float*)d_in[5];
    const float* ib1  = (const float*)d_in[6];
    const float* W2   = (const float*)d_in[7];
    const float* ib2  = (const float*)d_in[8];
    const float* Wq   = (const float*)d_in[9];
    const float* Wk   = (const float*)d_in[10];
    const float* Wv   = (const float*)d_in[11];
    const float* wih  = (const float*)d_in[12];
    /* lstm_whh d_in[13] unused: h0 == 0 */
    const float* lb   = (const float*)d_in[14];
    const float* Wout = (const float*)d_in[15];
    const float* ts     = (const float*)d_in[16];
    const float* n2_ts  = (const float*)d_in[17];
    const float* n1_ts  = (const float*)d_in[18];
    const float* n2_re  = (const float*)d_in[19];
    const float* n2_deg = (const float*)d_in[20];
    const float* n1_re  = (const float*)d_in[21];
    const float* n1_deg = (const float*)d_in[22];
    const int* center_nids = (const int*)d_in[23];
    const int* n2_nids     = (const int*)d_in[24];
    const int* n2_eids     = (const int*)d_in[25];
    const int* n1_nids     = (const int*)d_in[26];
    const int* n1_eids     = (const int*)d_in[27];

    // ---- workspace layout (HN aliases the dead Q|KQ|WFB region): ~36 MB ----
    float* ws  = (float*)d_ws;
    float* VW  = ws;                       // 484*256      = 123904
    float* qc0 = VW  + FEAT * DKQ;         // 256
    float* cv0 = qc0 + DKQ;                // 256
    float* CX  = cv0 + DKQ;                // 5120*128     = 655360
    float* H1  = CX  + NB1 * DIM;          // 5120*128     = 655360
    float* CTX = H1  + NB1 * DIM;          // 5120*256     = 1310720
    float* Q   = CTX + NB1 * DKQ;          // 5120*256     = 1310720
    float* KQ  = Q   + NB1 * DKQ;          // 5120*484     = 2478080
    float* WFB = KQ  + NB1 * FEAT;         // 5120*484     = 2478080
    float* HN  = Q;                        // 5120*1024 = 5242880 <= Q+KQ+WFB (6266880)
                                           // Q/KQ/WFB all dead before gates_hn_k runs

    precompute_k<<<FB + IMP + 2, 256, 0, stream>>>(tb, ib2, Wq, Wv, W2, VW, qc0, cv0);

    // ================= depth 1 (M = 5120) =================
    {
        const int M = NB1;
        cx_gather_k<<<M / 4, 128, 0, stream>>>(nr, ne, n2_nids, CX, M);
        gemm_f32<false><<<dim3(4, (M + 127) / 128), 256, 0, stream>>>(
            CX, nullptr, 0, 0, Wq, qc0, Q, M, DKQ, DIM, DIM, DKQ, DKQ, 0.0625f);
        gemm_f32<true><<<dim3(8, (M + 127) / 128), 256, 0, stream>>>(
            Q, nullptr, 0, 0, Wk, nullptr, KQ, M, FEAT, DKQ, DKQ, DKQ, FEAT, 1.f);
        attn_rows_k<1><<<M, 256, 0, stream>>>(nr, ne, ee, nullptr,
            n1_nids, n1_eids, n1_ts, n1_deg, n1_re, ts, tw, tb, iw1, ib1, W2, KQ, WFB);
        gemm_f32<false><<<dim3(4, (M + 127) / 128), 256, 0, stream>>>(
            WFB, nullptr, 0, 0, VW, cv0, CTX, M, DKQ, FEAT, FEAT, DKQ, DKQ, 1.f);
        gates_hn_k<<<dim3(16, M / 64), 256, 0, stream>>>(CTX, wih, lb, HN, M);
        gemm_f32<false><<<dim3(2, (M + 127) / 128), 256, 0, stream>>>(
            CX, HN, DIM, HID, Wout, nullptr, H1, M, DIM, DIM + HID, DIM, DIM, DIM, 1.f);
    }
    // ================= depth 2 (M = 256) =================
    {
        const int M = NB2;
        cx_gather_k<<<M / 4, 128, 0, stream>>>(nr, ne, center_nids, CX, M);
        gemm_f32<false><<<dim3(4, (M + 127) / 128), 256, 0, stream>>>(
            CX, nullptr, 0, 0, Wq, qc0, Q, M, DKQ, DIM, DIM, DKQ, DKQ, 0.0625f);
        gemm_f32<true><<<dim3(8, (M + 127) / 128), 256, 0, stream>>>(
            Q, nullptr, 0, 0, Wk, nullptr, KQ, M, FEAT, DKQ, DKQ, DKQ, FEAT, 1.f);
        attn_rows_k<2><<<M, 256, 0, stream>>>(nr, ne, ee, H1,
            n2_nids, n2_eids, n2_ts, n2_deg, n2_re, ts, tw, tb, iw1, ib1, W2, KQ, WFB);
        gemm_f32<false><<<dim3(4, (M + 127) / 128), 256, 0, stream>>>(
            WFB, nullptr, 0, 0, VW, cv0, CTX, M, DKQ, FEAT, FEAT, DKQ, DKQ, 1.f);
        gates_hn_k<<<dim3(16, M / 64), 256, 0, stream>>>(CTX, wih, lb, HN, M);
        gemm_f32<false><<<dim3(2, (M + 127) / 128), 256, 0, stream>>>(
            CX, HN, DIM, HID, Wout, nullptr, (float*)d_out, M, DIM, DIM + HID, DIM, DIM, DIM, 1.f);
    }
}

// Round 4
// 1237.214 us; speedup vs baseline: 1.1403x; 1.1403x over previous
//
#include <hip/hip_runtime.h>
#include <math.h>

// ---- problem constants ----
#define K_NB 20
#define DIM  128     // D
#define TDIM 128     // TD
#define IMP  100
#define DKQ  256     // DK
#define HID  1024    // H
#define FEAT 484
#define FB   384     // base feature cols (nx|ex|etx); imp cols via folded W2
#define NB1  5120    // B*K rows at depth 1
#define NB2  256     // B rows at depth 2
#define FROW 488     // featb row stride (484 + pad, 16B-aligned)

__device__ __forceinline__ float sigmoidf_(float x) { return 1.f / (1.f + expf(-x)); }

// ---------------------------------------------------------------------------
// P0: VW = [Wv[0:384] ; W2@Wv[384:484]], WK = [Wk[0:384] ; W2@Wk[384:484]],
//     qc0 = cos(time_b)@Wq[128:256],  cv0 = b2@Wv[384:484]
// ---------------------------------------------------------------------------
__global__ __launch_bounds__(256) void precompute_k(
    const float* __restrict__ time_b, const float* __restrict__ imp_b2,
    const float* __restrict__ Wq, const float* __restrict__ Wk,
    const float* __restrict__ Wv, const float* __restrict__ W2,
    float* __restrict__ VW, float* __restrict__ WK,
    float* __restrict__ qc0, float* __restrict__ cv0)
{
    int b = blockIdx.x, t = threadIdx.x;
    if (b < FB) {
        VW[b * DKQ + t] = Wv[b * DKQ + t];
        WK[b * DKQ + t] = Wk[b * DKQ + t];
    } else if (b < FB + IMP) {
        int j = b - FB; float aV = 0.f, aK = 0.f;
        for (int m = 0; m < IMP; m++) {
            float w = W2[j * IMP + m];
            aV += w * Wv[(FB + m) * DKQ + t];
            aK += w * Wk[(FB + m) * DKQ + t];
        }
        VW[b * DKQ + t] = aV;
        WK[b * DKQ + t] = aK;
    } else if (b == FB + IMP) {
        float acc = 0.f;
        for (int j = 0; j < TDIM; j++) acc += cosf(time_b[j]) * Wq[(DIM + j) * DKQ + t];
        qc0[t] = acc;
    } else {
        float acc = 0.f;
        for (int m = 0; m < IMP; m++) acc += imp_b2[m] * Wv[(FB + m) * DKQ + t];
        cv0[t] = acc;
    }
}

// ---------------------------------------------------------------------------
// CX[i][c] = node_reprs[cid][c] + node_embed[cid][c]; float4, 4 rows/block
// ---------------------------------------------------------------------------
__global__ __launch_bounds__(128) void cx_gather_k(
    const float* __restrict__ nr, const float* __restrict__ ne,
    const int* __restrict__ cids, float* __restrict__ CX, int nrows)
{
    int r = blockIdx.x * 4 + (threadIdx.x >> 5);
    if (r >= nrows) return;
    int c4 = (threadIdx.x & 31);
    int nid = cids[r];
    const float4 a = ((const float4*)(nr + (size_t)nid * DIM))[c4];
    const float4 b = ((const float4*)(ne + (size_t)nid * DIM))[c4];
    float4 o; o.x = a.x + b.x; o.y = a.y + b.y; o.z = a.z + b.z; o.w = a.w + b.w;
    ((float4*)(CX + (size_t)r * DIM))[c4] = o;
}

// ---------------------------------------------------------------------------
// Generic f32 GEMM: C[M,N] = (A|A2 concat at asplit)[M,K] @ B  (+bias)*scale
// BT=false: B is [K,N] row-major.  BT=true: B is [N,K] row-major (C=A@B^T).
// BM=128, BN=64, BK=16, 256 threads, 8x4 micro-tile.
// ---------------------------------------------------------------------------
template <bool BT>
__global__ __launch_bounds__(256) void gemm_f32(
    const float* __restrict__ A, const float* __restrict__ A2, int asplit, int lda2,
    const float* __restrict__ B, const float* __restrict__ bias,
    float* __restrict__ C, int M, int N, int K, int lda, int ldb, int ldc, float scale)
{
    __shared__ float As[16][132];
    __shared__ float Bs[16][68];
    const int tid = threadIdx.x;
    const int bm = blockIdx.y * 128, bn = blockIdx.x * 64;
    const int tm = (tid >> 4) * 8, tn = (tid & 15) * 4;
    float acc[8][4] = {};

    for (int k0 = 0; k0 < K; k0 += 16) {
        { // A tile: 128 rows x 16 k, 8 per thread
            int r = tid >> 1, kc = (tid & 1) * 8;
            int gr = bm + r;
#pragma unroll
            for (int i = 0; i < 8; i++) {
                int gk = k0 + kc + i;
                float v = 0.f;
                if (gr < M && gk < K)
                    v = (A2 && gk >= asplit) ? A2[gr * lda2 + (gk - asplit)] : A[gr * lda + gk];
                As[kc + i][r] = v;
            }
        }
        if (!BT) { // B[k][n]
            int kb = tid >> 4, nb = (tid & 15) * 4;
            int gk = k0 + kb;
#pragma unroll
            for (int i = 0; i < 4; i++) {
                int gn = bn + nb + i;
                Bs[kb][nb + i] = (gk < K && gn < N) ? B[gk * ldb + gn] : 0.f;
            }
        } else { // B[n][k] -> Bs[k][n]
            int n = tid >> 2, kc = (tid & 3) * 4;
            int gn = bn + n;
#pragma unroll
            for (int i = 0; i < 4; i++) {
                int gk = k0 + kc + i;
                Bs[kc + i][n] = (gn < N && gk < K) ? B[gn * ldb + gk] : 0.f;
            }
        }
        __syncthreads();
#pragma unroll
        for (int kk = 0; kk < 16; kk++) {
            float a[8], b[4];
#pragma unroll
            for (int i = 0; i < 8; i++) a[i] = As[kk][tm + i];
#pragma unroll
            for (int j = 0; j < 4; j++) b[j] = Bs[kk][tn + j];
#pragma unroll
            for (int i = 0; i < 8; i++)
#pragma unroll
                for (int j = 0; j < 4; j++) acc[i][j] += a[i] * b[j];
        }
        __syncthreads();
    }
#pragma unroll
    for (int i = 0; i < 8; i++) {
        int gm = bm + tm + i;
        if (gm >= M) continue;
#pragma unroll
        for (int j = 0; j < 4; j++) {
            int gn = bn + tn + j;
            if (gn >= N) continue;
            float v = acc[i][j];
            if (bias) v += bias[gn];
            C[gm * ldc + gn] = v * scale;
        }
    }
}

// ---------------------------------------------------------------------------
// attn_rows_k (restructured): 8 half-wave groups; group g gathers neighbor
// rr = g, g+8, g+16 with float4 loads, fusing the score dot-product.
// Wave-parallel softmax; float4 weighted-sum epilogue.
// featb row: [0:128) nx | [128:256) ex | [256:384) etx | [384:484) h
// KQ row (via WKmod) supplies all 484 score coefficients directly.
// ---------------------------------------------------------------------------
template <int DEPTH>
__global__ __launch_bounds__(256) void attn_rows_k(
    const float* __restrict__ nr, const float* __restrict__ ne,
    const float* __restrict__ ee, const float* __restrict__ h1,
    const int* __restrict__ nids, const int* __restrict__ eids,
    const float* __restrict__ nts, const float* __restrict__ deg,
    const float* __restrict__ re, const float* __restrict__ ts,
    const float* __restrict__ tw, const float* __restrict__ tb,
    const float* __restrict__ iw1, const float* __restrict__ ib1,
    const float* __restrict__ KQ, float* __restrict__ WFB)
{
    __shared__ float featb[K_NB][FROW];
    __shared__ float kq_s[FROW];
    __shared__ float score[K_NB], attn_l[K_NB];
    __shared__ float dt_s[K_NB], ss_s[K_NB];
    __shared__ int nid_s[K_NB], eid_s[K_NB];

    const int row = blockIdx.x, tid = threadIdx.x;
    const int g = tid >> 5, l = tid & 31;

    // ---- setup ----
    if (tid < K_NB) {
        int nid = nids[row * K_NB + tid];
        nid_s[tid] = nid; eid_s[tid] = eids[row * K_NB + tid];
        float tc = (DEPTH == 1) ? ts[row / K_NB] : ts[row];
        dt_s[tid] = tc - nts[row * K_NB + tid];
        float rv = re[row * K_NB + tid];
        ss_s[tid] = (rv == 0.f) ? 0.f : deg[row * K_NB + tid] / rv;
    }
    kq_s[tid] = KQ[(size_t)row * FEAT + tid];
    if (tid < FEAT - 256) kq_s[256 + tid] = KQ[(size_t)row * FEAT + 256 + tid];
    __syncthreads();

    // ---- gather + fused score ----
    for (int rr = g; rr < K_NB; rr += 8) {
        const int nid = nid_s[rr], eid = eid_s[rr];
        float4 xa;
        if (DEPTH == 1) {
            const float4 a = ((const float4*)(nr + (size_t)nid * DIM))[l];
            const float4 b = ((const float4*)(ne + (size_t)nid * DIM))[l];
            xa.x = a.x + b.x; xa.y = a.y + b.y; xa.z = a.z + b.z; xa.w = a.w + b.w;
        } else {
            xa = ((const float4*)(h1 + ((size_t)row * K_NB + rr) * DIM))[l];
        }
        const float4 xe = ((const float4*)(ee + (size_t)eid * DIM))[l];
        const float dt = dt_s[rr];
        const float4 tw4 = ((const float4*)tw)[l];
        const float4 tb4 = ((const float4*)tb)[l];
        float4 xt;
        xt.x = __cosf(dt * tw4.x + tb4.x);
        xt.y = __cosf(dt * tw4.y + tb4.y);
        xt.z = __cosf(dt * tw4.z + tb4.z);
        xt.w = __cosf(dt * tw4.w + tb4.w);

        ((float4*)&featb[rr][0])[l]   = xa;
        ((float4*)&featb[rr][128])[l] = xe;
        ((float4*)&featb[rr][256])[l] = xt;

        const int c = 4 * l;
        float sc = xa.x * kq_s[c]       + xa.y * kq_s[c + 1]       + xa.z * kq_s[c + 2]       + xa.w * kq_s[c + 3]
                 + xe.x * kq_s[128 + c] + xe.y * kq_s[128 + c + 1] + xe.z * kq_s[128 + c + 2] + xe.w * kq_s[128 + c + 3]
                 + xt.x * kq_s[256 + c] + xt.y * kq_s[256 + c + 1] + xt.z * kq_s[256 + c + 2] + xt.w * kq_s[256 + c + 3];
        if (l < IMP / 4) {
            const float s = ss_s[rr];
            const float4 w1 = ((const float4*)iw1)[l];
            const float4 b1 = ((const float4*)ib1)[l];
            float4 hv;
            hv.x = fmaxf(s * w1.x + b1.x, 0.f);
            hv.y = fmaxf(s * w1.y + b1.y, 0.f);
            hv.z = fmaxf(s * w1.z + b1.z, 0.f);
            hv.w = fmaxf(s * w1.w + b1.w, 0.f);
            ((float4*)&featb[rr][FB])[l] = hv;
            sc += hv.x * kq_s[FB + c] + hv.y * kq_s[FB + c + 1]
                + hv.z * kq_s[FB + c + 2] + hv.w * kq_s[FB + c + 3];
        }
#pragma unroll
        for (int off = 16; off >= 1; off >>= 1) sc += __shfl_down(sc, off, 32);
        if (l == 0) score[rr] = sc;
    }
    __syncthreads();

    // ---- wave-parallel softmax over 20 (lanes 20..31 padded to -3e38) ----
    if (tid < 32) {
        float sc = (tid < K_NB) ? ((nid_s[tid] == 0) ? -1e9f : score[tid]) : -3.0e38f;
        float mx = sc;
#pragma unroll
        for (int off = 16; off >= 1; off >>= 1) mx = fmaxf(mx, __shfl_xor(mx, off, 32));
        float e = __expf(sc - mx);
        float sum = e;
#pragma unroll
        for (int off = 16; off >= 1; off >>= 1) sum += __shfl_xor(sum, off, 32);
        if (tid < K_NB) attn_l[tid] = e / sum;
    }
    __syncthreads();

    // ---- weighted sum: 121 threads x float4 over 484 cols ----
    if (tid < FEAT / 4) {
        float4 acc = {0.f, 0.f, 0.f, 0.f};
#pragma unroll 4
        for (int r = 0; r < K_NB; r++) {
            const float a = attn_l[r];
            const float4 f = ((const float4*)&featb[r][0])[tid];
            acc.x += a * f.x; acc.y += a * f.y; acc.z += a * f.z; acc.w += a * f.w;
        }
        ((float4*)(WFB + (size_t)row * FEAT))[tid] = acc;   // 484*4 B = 16*121: aligned
    }
}

// ---------------------------------------------------------------------------
// HN = lstm(CTX @ wih[:, {i,g,o}] + b):  h = sig(o)*tanh(sig(i)*tanh(g))
// BM=64, BN=64 (of 1024), K=256. f-gate skipped (c_old = 0).
// ---------------------------------------------------------------------------
__global__ __launch_bounds__(256) void gates_hn_k(
    const float* __restrict__ CTX, const float* __restrict__ wih,
    const float* __restrict__ bias, float* __restrict__ HN, int M)
{
    __shared__ float As[16][68];
    __shared__ float Bs[3][16][68];
    const int tid = threadIdx.x;
    const int bm = blockIdx.y * 64, bn = blockIdx.x * 64;
    const int tm = (tid >> 4) * 4, tn = (tid & 15) * 4;
    float acc[3][4][4] = {};
    const int goff0 = 0, goff1 = 2048, goff2 = 3072;

    for (int k0 = 0; k0 < DKQ; k0 += 16) {
        int r = tid >> 2, kc = (tid & 3) * 4;
#pragma unroll
        for (int i = 0; i < 4; i++) As[kc + i][r] = CTX[(bm + r) * DKQ + k0 + kc + i];
        int kb = tid >> 4, nb = (tid & 15) * 4;
#pragma unroll
        for (int i = 0; i < 4; i++) {
            Bs[0][kb][nb + i] = wih[(k0 + kb) * 4096 + goff0 + bn + nb + i];
            Bs[1][kb][nb + i] = wih[(k0 + kb) * 4096 + goff1 + bn + nb + i];
            Bs[2][kb][nb + i] = wih[(k0 + kb) * 4096 + goff2 + bn + nb + i];
        }
        __syncthreads();
#pragma unroll
        for (int kk = 0; kk < 16; kk++) {
            float a[4], b0[4], b1[4], b2v[4];
#pragma unroll
            for (int i = 0; i < 4; i++) a[i] = As[kk][tm + i];
#pragma unroll
            for (int j = 0; j < 4; j++) {
                b0[j] = Bs[0][kk][tn + j]; b1[j] = Bs[1][kk][tn + j]; b2v[j] = Bs[2][kk][tn + j];
            }
#pragma unroll
            for (int i = 0; i < 4; i++)
#pragma unroll
                for (int j = 0; j < 4; j++) {
                    acc[0][i][j] += a[i] * b0[j];
                    acc[1][i][j] += a[i] * b1[j];
                    acc[2][i][j] += a[i] * b2v[j];
                }
        }
        __syncthreads();
    }
#pragma unroll
    for (int i = 0; i < 4; i++)
#pragma unroll
        for (int j = 0; j < 4; j++) {
            int n = bn + tn + j;
            float iv = acc[0][i][j] + bias[n];
            float gv = acc[1][i][j] + bias[2048 + n];
            float ov = acc[2][i][j] + bias[3072 + n];
            float c = sigmoidf_(iv) * tanhf(gv);
            HN[(bm + tm + i) * HID + n] = sigmoidf_(ov) * tanhf(c);
        }
}

// ---------------------------------------------------------------------------
extern "C" void kernel_launch(void* const* d_in, const int* in_sizes, int n_in,
                              void* d_out, int out_size, void* d_ws, size_t ws_size,
                              hipStream_t stream)
{
    const float* nr   = (const float*)d_in[0];
    const float* ne   = (const float*)d_in[1];
    const float* ee   = (const float*)d_in[2];
    const float* tw   = (const float*)d_in[3];
    const float* tb   = (const float*)d_in[4];
    const float* iw1  = (const float*)d_in[5];
    const float* ib1  = (const float*)d_in[6];
    const float* W2   = (const float*)d_in[7];
    const float* ib2  = (const float*)d_in[8];
    const float* Wq   = (const float*)d_in[9];
    const float* Wk   = (const float*)d_in[10];
    const float* Wv   = (const float*)d_in[11];
    const float* wih  = (const float*)d_in[12];
    /* lstm_whh d_in[13] unused: h0 == 0 */
    const float* lb   = (const float*)d_in[14];
    const float* Wout = (const float*)d_in[15];
    const float* ts     = (const float*)d_in[16];
    const float* n2_ts  = (const float*)d_in[17];
    const float* n1_ts  = (const float*)d_in[18];
    const float* n2_re  = (const float*)d_in[19];
    const float* n2_deg = (const float*)d_in[20];
    const float* n1_re  = (const float*)d_in[21];
    const float* n1_deg = (const float*)d_in[22];
    const int* center_nids = (const int*)d_in[23];
    const int* n2_nids     = (const int*)d_in[24];
    const int* n2_eids     = (const int*)d_in[25];
    const int* n1_nids     = (const int*)d_in[26];
    const int* n1_eids     = (const int*)d_in[27];

    // ---- workspace layout (HN aliases the dead Q|KQ|WFB region): ~37 MB ----
    float* ws  = (float*)d_ws;
    float* VW  = ws;                       // 484*256
    float* WK  = VW  + FEAT * DKQ;         // 484*256
    float* qc0 = WK  + FEAT * DKQ;         // 256
    float* cv0 = qc0 + DKQ;                // 256
    float* CX  = cv0 + DKQ;                // 5120*128
    float* H1  = CX  + NB1 * DIM;          // 5120*128
    float* CTX = H1  + NB1 * DIM;          // 5120*256
    float* Q   = CTX + NB1 * DKQ;          // 5120*256
    float* KQ  = Q   + NB1 * DKQ;          // 5120*484
    float* WFB = KQ  + NB1 * FEAT;         // 5120*484
    float* HN  = Q;                        // 5120*1024 fits in dead Q|KQ|WFB

    precompute_k<<<FB + IMP + 2, 256, 0, stream>>>(tb, ib2, Wq, Wk, Wv, W2, VW, WK, qc0, cv0);

    // ================= depth 1 (M = 5120) =================
    {
        const int M = NB1;
        cx_gather_k<<<M / 4, 128, 0, stream>>>(nr, ne, n2_nids, CX, M);
        gemm_f32<false><<<dim3(4, (M + 127) / 128), 256, 0, stream>>>(
            CX, nullptr, 0, 0, Wq, qc0, Q, M, DKQ, DIM, DIM, DKQ, DKQ, 0.0625f);
        gemm_f32<true><<<dim3(8, (M + 127) / 128), 256, 0, stream>>>(
            Q, nullptr, 0, 0, WK, nullptr, KQ, M, FEAT, DKQ, DKQ, DKQ, FEAT, 1.f);
        attn_rows_k<1><<<M, 256, 0, stream>>>(nr, ne, ee, nullptr,
            n1_nids, n1_eids, n1_ts, n1_deg, n1_re, ts, tw, tb, iw1, ib1, KQ, WFB);
        gemm_f32<false><<<dim3(4, (M + 127) / 128), 256, 0, stream>>>(
            WFB, nullptr, 0, 0, VW, cv0, CTX, M, DKQ, FEAT, FEAT, DKQ, DKQ, 1.f);
        gates_hn_k<<<dim3(16, M / 64), 256, 0, stream>>>(CTX, wih, lb, HN, M);
        gemm_f32<false><<<dim3(2, (M + 127) / 128), 256, 0, stream>>>(
            CX, HN, DIM, HID, Wout, nullptr, H1, M, DIM, DIM + HID, DIM, DIM, DIM, 1.f);
    }
    // ================= depth 2 (M = 256) =================
    {
        const int M = NB2;
        cx_gather_k<<<M / 4, 128, 0, stream>>>(nr, ne, center_nids, CX, M);
        gemm_f32<false><<<dim3(4, (M + 127) / 128), 256, 0, stream>>>(
            CX, nullptr, 0, 0, Wq, qc0, Q, M, DKQ, DIM, DIM, DKQ, DKQ, 0.0625f);
        gemm_f32<true><<<dim3(8, (M + 127) / 128), 256, 0, stream>>>(
            Q, nullptr, 0, 0, WK, nullptr, KQ, M, FEAT, DKQ, DKQ, DKQ, FEAT, 1.f);
        attn_rows_k<2><<<M, 256, 0, stream>>>(nr, ne, ee, H1,
            n2_nids, n2_eids, n2_ts, n2_deg, n2_re, ts, tw, tb, iw1, ib1, KQ, WFB);
        gemm_f32<false><<<dim3(4, (M + 127) / 128), 256, 0, stream>>>(
            WFB, nullptr, 0, 0, VW, cv0, CTX, M, DKQ, FEAT, FEAT, DKQ, DKQ, 1.f);
        gates_hn_k<<<dim3(16, M / 64), 256, 0, stream>>>(CTX, wih, lb, HN, M);
        gemm_f32<false><<<dim3(2, (M + 127) / 128), 256, 0, stream>>>(
            CX, HN, DIM, HID, Wout, nullptr, (float*)d_out, M, DIM, DIM + HID, DIM, DIM, DIM, 1.f);
    }
}